// Round 9
// baseline (236.897 us; speedup 1.0000x reference)
//
#include <hip/hip_runtime.h>

// SelfAttentionHead R16: 2 tiles per barrier in attn (sync-frequency /2).
//  qkv : R10 (reg-staged A, stage-time bf16 cvt, gl_lds16 B). Unchanged.
//  attn: R15 body (max-free softmax, R13 mapping) restructured to
//        process TWO 64-row K/V tiles per sync event. Double-buffered
//        tile-PAIRS (Kb/Vb[2][2][8KB], 73.7 KB LDS, still 2 blocks/CU);
//        group g covers tiles {2g, 2g+1}; prefetch of group g+1 issued
//        at group top (cover ~= 2 tile-computes >= HBM latency);
//        ONE vmcnt(0)+s_barrier per group (was one per tile). Stage and
//        barrier share the predicate 2(g+1) <= t. Tile b fragments are
//        read after tile a's compute (no VGPR doubling). Over-staging a
//        nonexistent 2nd tile touches valid in-batch rows (t < 31).
//        WAR: buf[1-p] was read at group g-1, reads retired (lgkm0)
//        before barrier(g-1) < stage at group g.
// Fragment maps (verified R2-R6): A[m=l15][k=Q*8+j] == B[k=Q*8+j][n=l15];
// C/D: col=l15, row=Q*4+reg. Operand swap == transposed product.
// XOR swizzle: 16B group g of row r stored at slot g^(r&7) [bf16 rows,
// 8 groups] -> frag ds_read_b128 at bank floor.

typedef __bf16 bf16x8 __attribute__((ext_vector_type(8)));
typedef __bf16 bf16x4 __attribute__((ext_vector_type(4)));
typedef float f32x4 __attribute__((ext_vector_type(4)));

constexpr int kE = 1024;
constexpr int kH = 64;
constexpr int kT = 2048;
constexpr int kB = 16;
constexpr int kM = kB * kT;
constexpr float kQScale = 0.125f * 1.44269504088896340736f;  // H^-0.5 * log2(e)

#define MFMA16(a, b, c) __builtin_amdgcn_mfma_f32_16x16x32_bf16((a), (b), (c), 0, 0, 0)

__device__ __forceinline__ void gl_lds16(const void* g, void* l) {
    __builtin_amdgcn_global_load_lds(
        (const __attribute__((address_space(1))) void*)g,
        (__attribute__((address_space(3))) void*)l, 16, 0, 0);
}

// ---------------------------------------------------------------- prep_w
__global__ __launch_bounds__(256)
void prep_w(const float* __restrict__ Wq, const float* __restrict__ Wk,
            const float* __restrict__ Wv, __bf16* __restrict__ WbT)
{
    __shared__ float tl[64][65];
    const int mat = blockIdx.x >> 4;
    const int k0 = (blockIdx.x & 15) * 64;
    const float* src = (mat == 0) ? Wq : (mat == 1) ? Wk : Wv;

    const int t = threadIdx.x;
    const int kr = t >> 2;
    const int cg = (t & 3) * 16;
    #pragma unroll
    for (int i = 0; i < 4; ++i) {
        float4 v = *(const float4*)&src[(size_t)(k0 + kr) * kH + cg + 4 * i];
        tl[cg + 4 * i + 0][kr] = v.x;
        tl[cg + 4 * i + 1][kr] = v.y;
        tl[cg + 4 * i + 2][kr] = v.z;
        tl[cg + 4 * i + 3][kr] = v.w;
    }
    __syncthreads();
    const int nl = t >> 2;
    const int kg = (t & 3) * 16;
    bf16x8 o0, o1;
    #pragma unroll
    for (int j = 0; j < 8; ++j) {
        o0[j] = (__bf16)tl[nl][kg + j];
        o1[j] = (__bf16)tl[nl][kg + 8 + j];
    }
    *(bf16x8*)&WbT[(size_t)(mat * 64 + nl) * kE + k0 + kg] = o0;
    *(bf16x8*)&WbT[(size_t)(mat * 64 + nl) * kE + k0 + kg + 8] = o1;
}

// ---------------------------------------------------------------- qkv
// 512 blocks, 256 threads (4 waves). Block: 64 rows x 192 cols (q|k|v).
// A-LDS (bf16): row r (0..63) x group g (0..7, 16B): byte = r*128 + (g^(r&7))*16
// B-LDS (bf16): row n (0..191) x group g (0..7): byte = n*128 + (g^(n&7))*16
// A staged via regs: load j (0..3) -> row w*16 + j*4 + (lane>>4),
// cols l15*4..+3 (per instr: 4 rows x 256 B, perfectly coalesced).
__global__ __launch_bounds__(256)
void qkv(const float* __restrict__ x, const __bf16* __restrict__ WbT,
         __bf16* __restrict__ qo, __bf16* __restrict__ ko, __bf16* __restrict__ vT)
{
    __shared__ __align__(16) char Ab[2][8192];
    __shared__ __align__(16) char Bb[2][24576];

    const int t = threadIdx.x;
    const int lane = t & 63;
    const int w = t >> 6;
    const int l15 = lane & 15;
    const int Q = lane >> 4;
    const int row0 = blockIdx.x * 64;

    f32x4 acc[4][3];
    #pragma unroll
    for (int mt = 0; mt < 4; ++mt)
        #pragma unroll
        for (int nt = 0; nt < 3; ++nt) acc[mt][nt] = (f32x4){0.f, 0.f, 0.f, 0.f};

    // B staging: per wave 6 KB DMA (6 instrs). Swizzle via global source.
    auto stageB = [&](int p, int k0) {
        #pragma unroll
        for (int i = 0; i < 6; ++i) {
            const int n = (w * 6 + i) * 8 + (lane >> 3);
            const int g = (lane & 7) ^ (lane >> 3);                 // slot ^ (n&7)
            gl_lds16(&WbT[(size_t)n * kE + k0 + g * 8],
                     &Bb[p][(w * 6 + i) * 1024]);
        }
    };

    // A reg staging: 4 coalesced float4 loads per lane (wave: 16 rows x 64 f32).
    float4 ar[4];
    auto loadA = [&](int k0) {
        #pragma unroll
        for (int j = 0; j < 4; ++j) {
            const int row = w * 16 + j * 4 + (lane >> 4);
            ar[j] = *(const float4*)&x[(size_t)(row0 + row) * kE + k0 + l15 * 4];
        }
    };
    // cvt once + swizzled ds_write_b64 (row r, cols l15*4..+3 ->
    // group l15>>1 half l15&1, slot = (l15>>1)^(r&7)).
    auto writeA = [&](int p) {
        #pragma unroll
        for (int j = 0; j < 4; ++j) {
            const int r = w * 16 + j * 4 + (lane >> 4);
            bf16x4 pk;
            pk[0] = (__bf16)ar[j].x; pk[1] = (__bf16)ar[j].y;
            pk[2] = (__bf16)ar[j].z; pk[3] = (__bf16)ar[j].w;
            *(bf16x4*)&Ab[p][r * 128 + (((l15 >> 1) ^ (r & 7)) * 16) + (l15 & 1) * 8] = pk;
        }
    };

    loadA(0);
    stageB(0, 0);
    writeA(0);
    __syncthreads();                 // chunk 0 ready (vmcnt B + lgkm A drain)

    for (int c = 0; c < 16; ++c) {
        const int p = c & 1;
        if (c < 15) {
            loadA((c + 1) * 64);     // issue early; cvt waits hidden by compute
            stageB(1 - p, (c + 1) * 64);
        }

        #pragma unroll
        for (int ks = 0; ks < 2; ++ks) {
            bf16x8 a4[4];
            #pragma unroll
            for (int mt = 0; mt < 4; ++mt) {
                const int row = mt * 16 + l15;
                a4[mt] = *(const bf16x8*)
                    &Ab[p][row * 128 + (((ks * 4 + Q) ^ (l15 & 7)) * 16)];
            }
            #pragma unroll
            for (int nt = 0; nt < 3; ++nt) {
                const int n = w * 48 + nt * 16 + l15;
                bf16x8 b = *(const bf16x8*)&Bb[p][n * 128 + (((ks * 4 + Q) ^ (l15 & 7)) * 16)];
                #pragma unroll
                for (int mt = 0; mt < 4; ++mt)
                    acc[mt][nt] = MFMA16(a4[mt], b, acc[mt][nt]);
            }
        }

        if (c < 15) writeA(1 - p);   // vmcnt auto-wait; buf released at prev barrier
        __syncthreads();             // publishes A writes (lgkm) + B DMA (vmcnt)
    }

    const int batch = row0 >> 11;
    const int tr0 = row0 & 2047;
    #pragma unroll
    for (int nt = 0; nt < 3; ++nt) {
        const int col0 = w * 48 + nt * 16;
        const int mat = col0 >> 6;
        const int c = (col0 & 63) + l15;
        if (mat == 2) {
            #pragma unroll
            for (int mt = 0; mt < 4; ++mt) {
                const int trow = tr0 + mt * 16 + Q * 4;
                bf16x4 pk;
                #pragma unroll
                for (int r = 0; r < 4; ++r) pk[r] = (__bf16)acc[mt][nt][r];
                *(bf16x4*)&vT[((size_t)batch * kH + c) * kT + trow] = pk;
            }
        } else {
            __bf16* dst = (mat == 0) ? qo : ko;
            const float sc_ = (mat == 0) ? kQScale : 1.0f;
            #pragma unroll
            for (int mt = 0; mt < 4; ++mt)
                #pragma unroll
                for (int r = 0; r < 4; ++r) {
                    const size_t row = row0 + mt * 16 + Q * 4 + r;
                    dst[row * kH + c] = (__bf16)(acc[mt][nt][r] * sc_);
                }
        }
    }
}

// ---------------------------------------------------------------- attn
// R16: 512 blocks x 256 threads (4 waves). R13 slot->t mapping. Groups
// of TWO 64-row tiles per sync event; double-buffered tile-pairs.
//   group g: [stage group g+1 if exists] -> tile 2g: reads,lgkm0,QK,
//   exp2,Ps,PV -> tile 2g+1 (if <= t): same -> vmcnt(0)+s_barrier
//   (only when group g+1 staged; predicates coincide).
// Max-free softmax (R15): P = exp2(S), no max, l_ per-lane partial
// reduced once after the loop. Masked: exp2(-3e38) == 0.
// K-LDS: row s (0..63) x group g (0..7): byte = s*128 + (g^(s&7))*16
// V-LDS: row h (0..63) x group g (0..7): byte = h*128 + (g^(h&7))*16
__global__ __launch_bounds__(256, 2)
void attn(const __bf16* __restrict__ qm, const __bf16* __restrict__ km,
          const __bf16* __restrict__ vT, float* __restrict__ out)
{
    __shared__ __align__(16) char Kb[2][2][8192];
    __shared__ __align__(16) char Vb[2][2][8192];
    __shared__ __align__(16) __bf16 Ps[4][16][72];

    const int tid = threadIdx.x;
    const int lane = tid & 63;
    const int w = tid >> 6;
    const int l15 = lane & 15;
    const int Q = lane >> 4;

    const int xcd  = blockIdx.x & 7;
    const int slot = blockIdx.x >> 3;
    const int batch = xcd + ((slot & 1) << 3);
    const int sh = slot & 31;
    const int tt = (slot < 32)
        ? ((slot & 1) ? (31 - (sh >> 1)) : (sh >> 1))
        : ((slot & 1) ? ((sh - 1) >> 1) : (31 - (sh >> 1)));
    const int q16 = tt * 4 + w;
    const int qrow = q16 * 16 + l15;
    const int last = tt;

    const __bf16* qb = qm + (size_t)batch * kT * kH;
    const __bf16* kb = km + (size_t)batch * kT * kH;
    const __bf16* vb = vT + (size_t)batch * kH * kT;

    // Stage a 2-tile group (128 s-rows) into buf p. Per wave: 8 gl_lds16.
    // 2nd tile may over-stage past the diagonal (valid in-batch rows).
    auto stageG = [&](int p, int g) {
        const int s0 = g * 128;
        #pragma unroll
        for (int tsub = 0; tsub < 2; ++tsub)
            #pragma unroll
            for (int i = 0; i < 2; ++i) {
                const int r = w * 16 + i * 8 + (lane >> 3);   // linear row
                const int gg = (lane & 7) ^ (lane >> 3);      // slot ^ (r&7)
                gl_lds16(&kb[(size_t)(s0 + tsub * 64 + r) * kH + gg * 8],
                         &Kb[p][tsub][(w * 2 + i) * 1024]);
                gl_lds16(&vb[(size_t)r * kT + s0 + tsub * 64 + gg * 8],
                         &Vb[p][tsub][(w * 2 + i) * 1024]);
            }
    };

    // Q fragment (B-operand of S^T)
    bf16x8 aq[2];
    aq[0] = *(const bf16x8*)&qb[(size_t)qrow * kH + Q * 8];
    aq[1] = *(const bf16x8*)&qb[(size_t)qrow * kH + 32 + Q * 8];

    f32x4 O[4];
    #pragma unroll
    for (int i = 0; i < 4; ++i) O[i] = (f32x4){0.f, 0.f, 0.f, 0.f};
    float l_ = 0.f;                       // per-lane partial denominator

    // One 64-row tile: fragments -> QK^T -> exp2 -> Ps round-trip -> PV.
    auto doTile = [&](const char* Kt, const char* Vt, int tile) {
        bf16x8 kf[8], vf[8];
        #pragma unroll
        for (int ks = 0; ks < 2; ++ks)
            #pragma unroll
            for (int nt = 0; nt < 4; ++nt)
                kf[ks * 4 + nt] = *(const bf16x8*)
                    &Kt[(nt * 16 + l15) * 128 + (((ks * 4 + Q) ^ (l15 & 7)) * 16)];
        #pragma unroll
        for (int ht = 0; ht < 4; ++ht)
            #pragma unroll
            for (int ss = 0; ss < 2; ++ss)
                vf[ht * 2 + ss] = *(const bf16x8*)
                    &Vt[(ht * 16 + l15) * 128 + (((ss * 4 + Q) ^ (l15 & 7)) * 16)];
        asm volatile("s_waitcnt lgkmcnt(0)" ::: "memory");   // reads retired

        f32x4 sacc[4];
        #pragma unroll
        for (int nt = 0; nt < 4; ++nt) sacc[nt] = (f32x4){0.f, 0.f, 0.f, 0.f};
        #pragma unroll
        for (int ks = 0; ks < 2; ++ks)
            #pragma unroll
            for (int nt = 0; nt < 4; ++nt)
                sacc[nt] = MFMA16(kf[ks * 4 + nt], aq[ks], sacc[nt]);

        if (tile == last) {   // diagonal tile mask (per-wave qrow)
            const int s0 = tile * 64;
            #pragma unroll
            for (int nt = 0; nt < 4; ++nt)
                #pragma unroll
                for (int r = 0; r < 4; ++r)
                    if (s0 + nt * 16 + Q * 4 + r > qrow) sacc[nt][r] = -3.0e38f;
        }

        // max-free softmax: P = exp2(S); l_ per-lane (in-lane tree).
        float snt[4];
        #pragma unroll
        for (int nt = 0; nt < 4; ++nt) {
            #pragma unroll
            for (int r = 0; r < 4; ++r)
                sacc[nt][r] = __builtin_amdgcn_exp2f(sacc[nt][r]);
            snt[nt] = (sacc[nt][0] + sacc[nt][1]) + (sacc[nt][2] + sacc[nt][3]);
        }
        l_ += (snt[0] + snt[1]) + (snt[2] + snt[3]);

        // P^T round-trip (per-wave strip; compiler orders via lgkmcnt)
        #pragma unroll
        for (int nt = 0; nt < 4; ++nt) {
            bf16x4 pk;
            #pragma unroll
            for (int r = 0; r < 4; ++r) pk[r] = (__bf16)sacc[nt][r];
            *(bf16x4*)&Ps[w][l15][nt * 16 + Q * 4] = pk;
        }
        bf16x8 pb0 = *(const bf16x8*)&Ps[w][l15][Q * 8];
        bf16x8 pb1 = *(const bf16x8*)&Ps[w][l15][32 + Q * 8];

        #pragma unroll
        for (int ht = 0; ht < 4; ++ht) {
            O[ht] = MFMA16(vf[ht * 2 + 0], pb0, O[ht]);
            O[ht] = MFMA16(vf[ht * 2 + 1], pb1, O[ht]);
        }
    };

    // Prologue: group 0 staged, published.
    stageG(0, 0);
    asm volatile("s_waitcnt vmcnt(0)" ::: "memory");
    __builtin_amdgcn_s_barrier();

    int p = 0;
    for (int g = 0; ; ++g) {
        const bool more = (2 * (g + 1) <= last);   // group g+1 exists
        if (more) stageG(1 - p, g + 1);            // full-group cover

        doTile(&Kb[p][0][0], &Vb[p][0][0], 2 * g);
        if (2 * g + 1 <= last)
            doTile(&Kb[p][1][0], &Vb[p][1][0], 2 * g + 1);

        if (!more) break;
        asm volatile("s_waitcnt vmcnt(0)" ::: "memory");   // group g+1 landed
        __builtin_amdgcn_s_barrier();                      // publish
        p ^= 1;
    }

    // denominator: reduce per-lane partials across the 4 Q-groups once
    l_ += __shfl_xor(l_, 16);
    l_ += __shfl_xor(l_, 32);
    const float inv = 1.0f / l_;
    float* orow = out + ((size_t)batch * kT + qrow) * kH;
    #pragma unroll
    for (int ht = 0; ht < 4; ++ht) {
        float4 o4;
        o4.x = O[ht][0] * inv; o4.y = O[ht][1] * inv;
        o4.z = O[ht][2] * inv; o4.w = O[ht][3] * inv;
        *(float4*)&orow[ht * 16 + Q * 4] = o4;
    }
}

extern "C" void kernel_launch(void* const* d_in, const int* in_sizes, int n_in,
                              void* d_out, int out_size, void* d_ws, size_t ws_size,
                              hipStream_t stream)
{
    (void)in_sizes; (void)n_in; (void)out_size; (void)ws_size;
    const float* x  = (const float*)d_in[0];
    const float* Wk = (const float*)d_in[1];
    const float* Wq = (const float*)d_in[2];
    const float* Wv = (const float*)d_in[3];

    __bf16* WbT  = (__bf16*)d_ws;                     // 384 KiB
    __bf16* qb   = WbT + (size_t)192 * kE;            // 4 MiB each
    __bf16* kbuf = qb + (size_t)kM * kH;
    __bf16* vT   = kbuf + (size_t)kM * kH;

    prep_w<<<48, 256, 0, stream>>>(Wq, Wk, Wv, WbT);
    qkv<<<kM / 64, 256, 0, stream>>>(x, WbT, qb, kbuf, vT);
    attn<<<512, 256, 0, stream>>>(qb, kbuf, vT, (float*)d_out);
}